// Round 4
// baseline (439.147 us; speedup 1.0000x reference)
//
#include <hip/hip_runtime.h>
#include <math.h>

// LIF spiking-neuron scan: N=65536 rows, T=512 sequential steps/row.
// d_out = [spikes (N*T) | mems (N*T)] fp32.
//
// History:
//  R2 direct per-lane global I/O  : ~2.5 TB/s eff (assumed kernel ~160us)
//  R3 LDS-staged TILE=32 depth-1  : ~2.5 TB/s
//  R4 TILE=64 depth-2 NT + 2-buf  : 363.0us total
//  R5 ROWS 64->16 (4 waves/SIMD)  : FAILED (compiler sank LDS reads past
//                                   cross-lane writes; fixed in R6)
//  R6 R5 + zero-cost WAVE_FENCE() : 361.6us total — concurrency REFUTED:
//                                   4x waves/SIMD, 2.5x DS issue = 0 delta.
//
// R7 — DECISIVE PROBE, NOT AN OPTIMIZATION. Three structurally different
// kernels (R2/R4/R6) all land at ~362+-2% total. Two decompositions fit:
//   (a) dur = poison(165) + kernel(~160) + gaps  -> kernel 2.5x off roofline
//   (b) dur = poison(~330) + kernel(~40)         -> kernel already ~BW floor
// They differ 4x in the kernel's true cost and dictate opposite strategies.
// The kernel's own rocprof row is unobtainable (top-5 saturated by fills).
// So: launch the BYTE-IDENTICAL R6 kernel TWICE on the same stream.
// Second launch recomputes bit-identical outputs (kernel never reads out;
// inputs const) — correctness and graph capture unaffected.
//   ===>  dur_R7 - 361.6 = exactly one kernel duration.  <===
// Pre-committed: delta 150-170 -> optimize kernel next (all-b128 LDS,
// stride-68); delta 40-70 -> kernel is at the traffic floor (403MB/6.3TBs
// = 64us), revert to single launch and declare roofline.
//
// NUMERICS: bit-exact vs numpy verified in R1/R2 — no FMA contraction on
// the recurrence (__f*_rn intrinsics only), sigmoid(beta_) double-rounded
// once to fp32. Do not change.

typedef float f32x4 __attribute__((ext_vector_type(4)));

// Compiler-only memory fence: forbids reordering memory ops across this
// point. Emits NOTHING. Required at every phase boundary (see R5 bug).
#define WAVE_FENCE() asm volatile("" ::: "memory")

constexpr int N_BATCH = 65536;
constexpr int T_STEPS = 512;
constexpr int BLOCK   = 64;              // ONE wave — wave-synchronous
constexpr int ROWS    = 16;              // rows per block (compute lanes 0..15)
constexpr int TILE    = 64;              // steps per chunk = 256B per row
constexpr int NCH     = T_STEPS / TILE;  // 8 chunks
constexpr int PAD     = TILE + 1;        // LDS row stride: 65 -> <=2-way banks (free)
constexpr int RPF     = T_STEPS / 4;     // 128: global row pitch in float4
constexpr int LPC     = ROWS * TILE / (BLOCK * 4);  // 4 load instrs per chunk

__device__ __forceinline__ void prefetch_chunk(f32x4 (&v)[LPC], const f32x4* __restrict__ xg,
                                               int base, int rsub, int a, int c) {
#pragma unroll
    for (int p = 0; p < LPC; ++p)
        v[p] = __builtin_nontemporal_load(
            &xg[(size_t)(base + p * 4 + rsub) * RPF + (size_t)c * 16 + a]);
}

__device__ __forceinline__ void stage_chunk(const f32x4 (&v)[LPC], float* xs, int rsub, int a) {
#pragma unroll
    for (int p = 0; p < LPC; ++p) {
        const int r = p * 4 + rsub;
        float* dst = &xs[r * PAD + a * 4];
        dst[0] = v[p][0]; dst[1] = v[p][1]; dst[2] = v[p][2]; dst[3] = v[p][3];
    }
}

__device__ __forceinline__ void store_chunk(const float* xs, const float* msb,
                                            f32x4* __restrict__ sg, f32x4* __restrict__ mg,
                                            int base, int rsub, int a, int c) {
#pragma unroll
    for (int p = 0; p < LPC; ++p) {
        const int r = p * 4 + rsub;
        const float* srow = &xs [r * PAD + a * 4];
        const float* mrow = &msb[r * PAD + a * 4];
        const f32x4 sv = { srow[0], srow[1], srow[2], srow[3] };
        const f32x4 mv = { mrow[0], mrow[1], mrow[2], mrow[3] };
        const size_t gi = (size_t)(base + r) * RPF + (size_t)c * 16 + a;
        __builtin_nontemporal_store(sv, &sg[gi]);
        __builtin_nontemporal_store(mv, &mg[gi]);
    }
}

__global__ __launch_bounds__(BLOCK, 1) void lif_scan_kernel(
    const float* __restrict__ x,
    const float* __restrict__ beta_p,
    const float* __restrict__ thr_p,
    const float* __restrict__ init_u,
    float* __restrict__ out)
{
#pragma clang fp contract(off)
    __shared__ float xs [ROWS * PAD];   // x tile in, spike tile out (reused in place)
    __shared__ float msb[ROWS * PAD];   // mems tile

    const int t    = threadIdx.x;       // 0..63
    const int base = blockIdx.x * ROWS;
    const int rsub = t >> 4;            // 0..3: row-within-pass for I/O role
    const int a    = t & 15;            // 0..15: float4 index within 256B chunk

    const float thr  = thr_p[0];
    const float beta = (float)(1.0 / (1.0 + exp(-(double)beta_p[0])));
    float mem = 0.0f;
    if (t < ROWS) mem = __fmul_rn(init_u[base + t], thr);   // mem0, row base+t

    const f32x4* __restrict__ xg = (const f32x4*)x;
    f32x4* __restrict__ sg = (f32x4*)out;
    f32x4* __restrict__ mg = (f32x4*)(out + (size_t)N_BATCH * T_STEPS);

    f32x4 va[LPC], vb[LPC];
    prefetch_chunk(va, xg, base, rsub, a, 0);
    prefetch_chunk(vb, xg, base, rsub, a, 1);

    // compute: lane t (<ROWS) scans row base+t over TILE steps.
    // (wave-synchronous: HW DS pipe in-order; WAVE_FENCE pins compiler order)
    auto compute_chunk = [&]() {
#pragma clang fp contract(off)
        if (t < ROWS) {
#pragma unroll
            for (int k = 0; k < TILE; ++k) {
                const float xv      = xs[t * PAD + k];
                const float mem_in  = mem;
                const float mem_upd = __fadd_rn(__fmul_rn(beta, mem), xv);
                const float surplus = __fsub_rn(mem_upd, thr);
                const float hard    = (surplus >= 0.0f) ? 1.0f : 0.0f;
                xs [t * PAD + k] = hard;     // spike forward == hard (overwrites consumed x)
                msb[t * PAD + k] = mem_in;   // mems logs memory BEFORE the step
                mem = __fsub_rn(mem_upd, __fmul_rn(hard, thr));
            }
        }
    };

    for (int c = 0; c < NCH; c += 2) {
        // ---- even chunk: data in va ----
        stage_chunk(va, xs, rsub, a);                          // waits on va loads only
        if (c + 2 < NCH) prefetch_chunk(va, xg, base, rsub, a, c + 2);
        WAVE_FENCE();   // stage xs writes  || compute xs reads
        compute_chunk();
        WAVE_FENCE();   // compute xs/msb writes || store reads
        store_chunk(xs, msb, sg, mg, base, rsub, a, c);
        WAVE_FENCE();   // store reads || next stage/compute writes

        // ---- odd chunk: data in vb ----
        stage_chunk(vb, xs, rsub, a);
        if (c + 3 < NCH) prefetch_chunk(vb, xg, base, rsub, a, c + 3);
        WAVE_FENCE();
        compute_chunk();
        WAVE_FENCE();
        store_chunk(xs, msb, sg, mg, base, rsub, a, c + 1);
        WAVE_FENCE();
    }
}

extern "C" void kernel_launch(void* const* d_in, const int* in_sizes, int n_in,
                              void* d_out, int out_size, void* d_ws, size_t ws_size,
                              hipStream_t stream) {
    const float* x      = (const float*)d_in[0];
    const float* beta_  = (const float*)d_in[1];
    const float* thresh = (const float*)d_in[2];
    const float* init_u = (const float*)d_in[3];
    float* out = (float*)d_out;

    dim3 block(BLOCK);
    dim3 grid(N_BATCH / ROWS);   // 4096 blocks -> 16 per CU (4 waves/SIMD)

    // PROBE: launch twice (serialized on the stream; bit-identical outputs).
    // dur_us(R7) - dur_us(R6=361.6) == one true kernel duration.
    lif_scan_kernel<<<grid, block, 0, stream>>>(x, beta_, thresh, init_u, out);
    lif_scan_kernel<<<grid, block, 0, stream>>>(x, beta_, thresh, init_u, out);
}

// Round 5
// 361.015 us; speedup vs baseline: 1.2164x; 1.2164x over previous
//
#include <hip/hip_runtime.h>
#include <math.h>

// LIF spiking-neuron scan: N=65536 rows, T=512 sequential steps/row.
// d_out = [spikes (N*T) | mems (N*T)] fp32.
//
// History:
//  R2 direct per-lane global I/O  : 362us total
//  R4 TILE=64 depth-2 NT + 2-buf  : 363.0us total
//  R6 ROWS=16 (4 waves/SIMD) + WAVE_FENCE : 361.6us total
//  R7 PROBE: R6 kernel launched twice -> 439.1us. KERNEL = 77.5us.
//     => dur = ~284us harness poison-fill overhead (untouchable) + kernel.
//     R2-R6's "2.5 TB/s" was mis-attribution of fill time to the kernel;
//     that's why three structural rewrites were all null. Kernel actual:
//     403MB/77.5us = 5.2 TB/s vs 6.3 TB/s mixed-stream achievable.
//
// R8 theory — the kernel is LDS-INSTRUCTION-bound, not HBM-bound:
// PAD=65 made every f32x4 LDS access 16B-misaligned (row stride 260B) ->
// compiler emits scalar ds_*_b32. Per wave per chunk: stage 16 + compute
// 192 + store 32 = 240 DS instrs; per CU 16 waves x 8 chunks x 240 =
// 30,720 DS instrs x ~4-5.8cyc (m134) = 51-74us of LDS-pipe serialization
// ~= the measured 77.5us.
// Fix: PAD=68 (272B row stride: 16B-aligned, 68%32=4 -> <=2 touches/bank,
// free) and pack ALL LDS traffic as b128: stage 4 ds_write_b128, compute
// 16 read + 32 write b128 (4 steps per vector, quads packed in regs),
// store 8 ds_read_b128. 240 -> 60 DS instrs/wave/chunk -> DS pipe time
// ~15-30us/CU, below the ~64us HBM floor. Global I/O, concurrency,
// fences unchanged. Single launch restored.
// Predict: kernel 77.5 -> ~64-68us; dur 361.6 -> ~348-353. If null:
// kernel was at its mixed-stream HBM ceiling -> declare roofline.
//
// NUMERICS: bit-exact vs numpy verified — no FMA contraction on the
// recurrence (__f*_rn intrinsics only), sigmoid(beta_) double-rounded
// once to fp32. Do not change.
//
// R5 bug (kept fixed): compiler may reorder cross-lane LDS deps it can
// prove per-thread-disjoint; WAVE_FENCE() (zero-cost compiler fence) at
// every phase boundary pins program order; HW DS pipe is in-order.

typedef float f32x4 __attribute__((ext_vector_type(4)));

#define WAVE_FENCE() asm volatile("" ::: "memory")

constexpr int N_BATCH = 65536;
constexpr int T_STEPS = 512;
constexpr int BLOCK   = 64;              // ONE wave — wave-synchronous
constexpr int ROWS    = 16;              // rows per block (compute lanes 0..15)
constexpr int TILE    = 64;              // steps per chunk = 256B per row
constexpr int NCH     = T_STEPS / TILE;  // 8 chunks
constexpr int PAD     = 68;              // floats/row: 272B = 16B-aligned, 68%32=4 -> conflict-free
constexpr int RPF     = T_STEPS / 4;     // 128: global row pitch in float4
constexpr int LPC     = ROWS * TILE / (BLOCK * 4);  // 4 load instrs per chunk

// I/O lane roles: rsub = t>>4 (0..3), a = t&15 (float4 within the 256B
// chunk). Instruction p covers rows p*4+rsub -> 4 rows x 256B = 8 full
// 128B lines per instruction.

__device__ __forceinline__ void prefetch_chunk(f32x4 (&v)[LPC], const f32x4* __restrict__ xg,
                                               int base, int rsub, int a, int c) {
#pragma unroll
    for (int p = 0; p < LPC; ++p)
        v[p] = __builtin_nontemporal_load(
            &xg[(size_t)(base + p * 4 + rsub) * RPF + (size_t)c * 16 + a]);
}

__device__ __forceinline__ void stage_chunk(const f32x4 (&v)[LPC], float* xs, int rsub, int a) {
#pragma unroll
    for (int p = 0; p < LPC; ++p) {
        const int r = p * 4 + rsub;
        ((f32x4*)&xs[r * PAD])[a] = v[p];          // one ds_write_b128, 16B-aligned
    }
}

__device__ __forceinline__ void store_chunk(const float* xs, const float* msb,
                                            f32x4* __restrict__ sg, f32x4* __restrict__ mg,
                                            int base, int rsub, int a, int c) {
#pragma unroll
    for (int p = 0; p < LPC; ++p) {
        const int r = p * 4 + rsub;
        const f32x4 sv = ((const f32x4*)&xs [r * PAD])[a];   // ds_read_b128
        const f32x4 mv = ((const f32x4*)&msb[r * PAD])[a];   // ds_read_b128
        const size_t gi = (size_t)(base + r) * RPF + (size_t)c * 16 + a;
        __builtin_nontemporal_store(sv, &sg[gi]);
        __builtin_nontemporal_store(mv, &mg[gi]);
    }
}

__global__ __launch_bounds__(BLOCK, 1) void lif_scan_kernel(
    const float* __restrict__ x,
    const float* __restrict__ beta_p,
    const float* __restrict__ thr_p,
    const float* __restrict__ init_u,
    float* __restrict__ out)
{
#pragma clang fp contract(off)
    __shared__ float xs [ROWS * PAD];   // x tile in, spike tile out (reused in place)
    __shared__ float msb[ROWS * PAD];   // mems tile

    const int t    = threadIdx.x;       // 0..63
    const int base = blockIdx.x * ROWS;
    const int rsub = t >> 4;            // 0..3: row-within-pass for I/O role
    const int a    = t & 15;            // 0..15: float4 index within 256B chunk

    const float thr  = thr_p[0];
    const float beta = (float)(1.0 / (1.0 + exp(-(double)beta_p[0])));
    float mem = 0.0f;
    if (t < ROWS) mem = __fmul_rn(init_u[base + t], thr);   // mem0, row base+t

    const f32x4* __restrict__ xg = (const f32x4*)x;
    f32x4* __restrict__ sg = (f32x4*)out;
    f32x4* __restrict__ mg = (f32x4*)(out + (size_t)N_BATCH * T_STEPS);

    f32x4 va[LPC], vb[LPC];
    prefetch_chunk(va, xg, base, rsub, a, 0);
    prefetch_chunk(vb, xg, base, rsub, a, 1);

    // compute: lane t (<ROWS) scans row base+t over TILE steps, 4 at a time:
    // 1 ds_read_b128 + 4 scan steps in regs + 2 ds_write_b128 per quad.
    // Same-address read->write on xs row forces in-place order; cross-lane
    // hazards are at phase boundaries only, guarded by WAVE_FENCE.
    auto compute_chunk = [&]() {
#pragma clang fp contract(off)
        if (t < ROWS) {
            f32x4* xrow = (f32x4*)&xs [t * PAD];
            f32x4* mrow = (f32x4*)&msb[t * PAD];
#pragma unroll
            for (int q = 0; q < TILE / 4; ++q) {
                const f32x4 xv4 = xrow[q];
                f32x4 sv, mv;
#pragma unroll
                for (int j = 0; j < 4; ++j) {
                    const float mem_in  = mem;
                    const float mem_upd = __fadd_rn(__fmul_rn(beta, mem), xv4[j]);
                    const float surplus = __fsub_rn(mem_upd, thr);
                    const float hard    = (surplus >= 0.0f) ? 1.0f : 0.0f;
                    sv[j] = hard;       // spike forward value == hard
                    mv[j] = mem_in;     // mems logs memory BEFORE the step
                    mem = __fsub_rn(mem_upd, __fmul_rn(hard, thr));
                }
                xrow[q] = sv;           // overwrites consumed x quad (in place)
                mrow[q] = mv;
            }
        }
    };

    for (int c = 0; c < NCH; c += 2) {
        // ---- even chunk: data in va ----
        stage_chunk(va, xs, rsub, a);                          // waits on va loads only
        if (c + 2 < NCH) prefetch_chunk(va, xg, base, rsub, a, c + 2);
        WAVE_FENCE();   // stage xs writes  || compute xs reads
        compute_chunk();
        WAVE_FENCE();   // compute xs/msb writes || store reads
        store_chunk(xs, msb, sg, mg, base, rsub, a, c);
        WAVE_FENCE();   // store reads || next stage/compute writes

        // ---- odd chunk: data in vb ----
        stage_chunk(vb, xs, rsub, a);
        if (c + 3 < NCH) prefetch_chunk(vb, xg, base, rsub, a, c + 3);
        WAVE_FENCE();
        compute_chunk();
        WAVE_FENCE();
        store_chunk(xs, msb, sg, mg, base, rsub, a, c + 1);
        WAVE_FENCE();
    }
}

extern "C" void kernel_launch(void* const* d_in, const int* in_sizes, int n_in,
                              void* d_out, int out_size, void* d_ws, size_t ws_size,
                              hipStream_t stream) {
    const float* x      = (const float*)d_in[0];
    const float* beta_  = (const float*)d_in[1];
    const float* thresh = (const float*)d_in[2];
    const float* init_u = (const float*)d_in[3];
    float* out = (float*)d_out;

    dim3 block(BLOCK);
    dim3 grid(N_BATCH / ROWS);   // 4096 blocks -> 16 per CU (4 waves/SIMD)
    lif_scan_kernel<<<grid, block, 0, stream>>>(x, beta_, thresh, init_u, out);
}